// Round 5
// baseline (577.489 us; speedup 1.0000x reference)
//
#include <hip/hip_runtime.h>

#define N_NODES 100000
#define N_RELS  500
#define N_EDGES 1000000

// workspace layout (float offsets)
#define OFF_C     0        // 1
#define OFF_SUMS  64       // 64
#define OFF_SUMSQ 128      // 64
#define OFF_SS    192      // 128 (scale|shift, x-branch)
#define OFF_RSUM  320      // 64
#define OFF_RSQ   384      // 64
#define OFF_RSS   448      // 128 (scale|shift, r-branch)
#define OFF_SR    576      // 500
#define OFF_RP    1088     // 32000 (r-branch pre-BN)
#define OFF_SX    33152    // 100000
#define OFF_CS    133152   // 100000
#define OFF_PR    233216   // 32000
#define OFF_PX    265216   // 6400000
#define OFF_ACC   6665216  // 6400000
// total 13,065,216 floats = 52.3 MB

// ---- c = b_m . aw_m + aw_q . que -------------------------------------------
__global__ void k_prep(const float* __restrict__ aw, const float* __restrict__ bm,
                       const float* __restrict__ que, float* __restrict__ ws) {
    int t = threadIdx.x;  // 64
    float v = aw[t] * bm[t] + aw[64 + t] * que[t];
    for (int o = 32; o > 0; o >>= 1) v += __shfl_down(v, o);
    if (t == 0) ws[OFF_C] = v;
}

// ---- pr[k][l] = W_m[l][64:] . r[k], sr[k] = pr[k] . aw_m --------------------
__global__ void __launch_bounds__(256) k_pr(const float* __restrict__ r, const float* __restrict__ Wm,
                                            const float* __restrict__ aw, float* __restrict__ ws) {
    __shared__ float w[64][65];
    __shared__ float awl[64];
    int tid = threadIdx.x;
    for (int i = tid; i < 4096; i += 256) w[i >> 6][i & 63] = Wm[(i >> 6) * 128 + 64 + (i & 63)];
    if (tid < 64) awl[tid] = aw[tid];
    __syncthreads();
    int lane = tid & 63, wv = tid >> 6;
    int i = blockIdx.x * 4 + wv;  // grid 125 -> exactly 500
    float rv = r[i * 64 + lane];
    float p = 0.f;
#pragma unroll
    for (int k = 0; k < 64; ++k) p += w[lane][k] * __shfl(rv, k);
    ws[OFF_PR + i * 64 + lane] = p;
    float t = p * awl[lane];
    for (int o = 32; o > 0; o >>= 1) t += __shfl_down(t, o);
    if (lane == 0) ws[OFF_SR + i] = t;
}

// ---- px[n][l] = W_m[l][:64] . x[n], sx[n] = px[n] . aw_m --------------------
__global__ void __launch_bounds__(256) k_px(const float* __restrict__ x, const float* __restrict__ Wm,
                                            const float* __restrict__ aw, float* __restrict__ ws) {
    __shared__ float w[64][65];
    __shared__ float awl[64];
    int tid = threadIdx.x;
    for (int i = tid; i < 4096; i += 256) w[i >> 6][i & 63] = Wm[(i >> 6) * 128 + (i & 63)];
    if (tid < 64) awl[tid] = aw[tid];
    __syncthreads();
    int lane = tid & 63, wv = tid >> 6;
    int base = blockIdx.x * 32 + wv * 8;  // grid 3125 -> exactly 100000
    for (int nn = 0; nn < 8; ++nn) {
        int n = base + nn;
        float xv = x[(size_t)n * 64 + lane];
        float p = 0.f;
#pragma unroll
        for (int k = 0; k < 64; ++k) p += w[lane][k] * __shfl(xv, k);
        ws[OFF_PX + (size_t)n * 64 + lane] = p;
        float t = p * awl[lane];
        for (int o = 32; o > 0; o >>= 1) t += __shfl_down(t, o);
        if (lane == 0) ws[OFF_SX + n] = t;
    }
}

// ---- coeffs_sum: atomic sum of exp(tanh(logit)) per target ------------------
__global__ void __launch_bounds__(256) k_edge1(const int* __restrict__ ei, const int* __restrict__ ea,
                                               float* __restrict__ ws) {
    int e = blockIdx.x * 256 + threadIdx.x;
    if (e >= N_EDGES) return;
    int src = ei[e], tgt = ei[N_EDGES + e], at = ea[e];
    float a = __expf(tanhf(ws[OFF_SX + src] + ws[OFF_SR + at] + ws[OFF_C]));
    atomicAdd(&ws[OFF_CS + tgt], a);
}

// ---- weighted scatter: acc[tgt] += w * (px[src] + pr[at]) -------------------
__global__ void __launch_bounds__(256) k_edge2(const int* __restrict__ ei, const int* __restrict__ ea,
                                               float* __restrict__ ws) {
    int wid = (blockIdx.x * 256 + threadIdx.x) >> 6;  // wave per edge, grid exact
    int lane = threadIdx.x & 63;
    int src = ei[wid], tgt = ei[N_EDGES + wid], at = ea[wid];
    float a = __expf(tanhf(ws[OFF_SX + src] + ws[OFF_SR + at] + ws[OFF_C]));
    float wgt = a / ws[OFF_CS + tgt];
    float val = wgt * (ws[OFF_PX + (size_t)src * 64 + lane] + ws[OFF_PR + at * 64 + lane]);
    atomicAdd(&ws[OFF_ACC + (size_t)tgt * 64 + lane], val);
}

// ---- x-branch BN column stats ----------------------------------------------
__global__ void __launch_bounds__(256) k_stats(const float* __restrict__ bm, float* __restrict__ ws) {
    __shared__ float bsum[64], bsq[64];
    int tid = threadIdx.x;
    if (tid < 64) { bsum[tid] = 0.f; bsq[tid] = 0.f; }
    __syncthreads();
    int lane = tid & 63, wv = tid >> 6;
    float ls = 0.f, lq = 0.f;
    int base = blockIdx.x * 64;
    for (int it = 0; it < 16; ++it) {
        int t = base + it * 4 + wv;
        if (t < N_NODES) {
            float p = ws[OFF_ACC + (size_t)t * 64 + lane] + (ws[OFF_CS + t] > 0.f ? bm[lane] : 0.f);
            ls += p; lq += p * p;
        }
    }
    atomicAdd(&bsum[lane], ls);
    atomicAdd(&bsq[lane], lq);
    __syncthreads();
    if (tid < 64) {
        atomicAdd(&ws[OFF_SUMS + tid], bsum[tid]);
        atomicAdd(&ws[OFF_SUMSQ + tid], bsq[tid]);
    }
}

// ---- r-branch: pre-BN GEMM + column stats ----------------------------------
__global__ void __launch_bounds__(256) k_rpre(const float* __restrict__ r, const float* __restrict__ Wr,
                                              const float* __restrict__ br, float* __restrict__ ws) {
    __shared__ float w[64][65];
    int tid = threadIdx.x;
    for (int i = tid; i < 4096; i += 256) w[i >> 6][i & 63] = Wr[(i >> 6) * 64 + (i & 63)];
    __syncthreads();
    int lane = tid & 63, wv = tid >> 6;
    int i = blockIdx.x * 4 + wv;  // grid 125 -> exactly 500
    float rv = r[i * 64 + lane];
    float p = br[lane];
#pragma unroll
    for (int k = 0; k < 64; ++k) p += w[lane][k] * __shfl(rv, k);
    ws[OFF_RP + i * 64 + lane] = p;
    atomicAdd(&ws[OFF_RSUM + lane], p);
    atomicAdd(&ws[OFF_RSQ + lane], p * p);
}

// ---- finalize both BN scale/shift ------------------------------------------
__global__ void k_bnfin(float* __restrict__ ws, const float* __restrict__ eg, const float* __restrict__ eb,
                        const float* __restrict__ rg, const float* __restrict__ rb) {
    int tid = threadIdx.x;  // 128
    if (tid < 64) {
        int j = tid;
        float mean = ws[OFF_SUMS + j] * (1.f / N_NODES);
        float var = ws[OFF_SUMSQ + j] * (1.f / N_NODES) - mean * mean;
        float sc = rsqrtf(var + 1e-5f) * eg[j];
        ws[OFF_SS + j] = sc;
        ws[OFF_SS + 64 + j] = eb[j] - mean * sc;
    } else {
        int j = tid - 64;
        float mean = ws[OFF_RSUM + j] * (1.f / N_RELS);
        float var = ws[OFF_RSQ + j] * (1.f / N_RELS) - mean * mean;
        float sc = rsqrtf(var + 1e-5f) * rg[j];
        ws[OFF_RSS + j] = sc;
        ws[OFF_RSS + 64 + j] = rb[j] - mean * sc;
    }
}

// ---- x-branch output --------------------------------------------------------
__global__ void __launch_bounds__(256) k_xout(const float* __restrict__ bm, const float* __restrict__ ws,
                                              float* __restrict__ out) {
    __shared__ float sc[64], sh[64];
    int tid = threadIdx.x;
    if (tid < 64) { sc[tid] = ws[OFF_SS + tid]; sh[tid] = ws[OFF_SS + 64 + tid]; }
    __syncthreads();
    int lane = tid & 63, wv = tid >> 6;
    int base = blockIdx.x * 64;
    for (int it = 0; it < 16; ++it) {
        int t = base + it * 4 + wv;
        if (t < N_NODES) {
            float p = ws[OFF_ACC + (size_t)t * 64 + lane] + (ws[OFF_CS + t] > 0.f ? bm[lane] : 0.f);
            out[(size_t)t * 64 + lane] = tanhf(p * sc[lane] + sh[lane]);
        }
    }
}

// ---- r-branch output --------------------------------------------------------
__global__ void __launch_bounds__(256) k_rout(const float* __restrict__ ws, float* __restrict__ out) {
    __shared__ float sc[64], sh[64];
    int tid = threadIdx.x;
    if (tid < 64) { sc[tid] = ws[OFF_RSS + tid]; sh[tid] = ws[OFF_RSS + 64 + tid]; }
    __syncthreads();
    int lane = tid & 63, wv = tid >> 6;
    int i = blockIdx.x * 4 + wv;  // grid 125
    float p = ws[OFF_RP + i * 64 + lane];
    out[(size_t)N_NODES * 64 + (size_t)i * 64 + lane] = tanhf(p * sc[lane] + sh[lane]);
}

extern "C" void kernel_launch(void* const* d_in, const int* in_sizes, int n_in,
                              void* d_out, int out_size, void* d_ws, size_t ws_size,
                              hipStream_t stream) {
    const float* x   = (const float*)d_in[0];
    const float* r   = (const float*)d_in[1];
    const float* que = (const float*)d_in[2];
    const int*   ei  = (const int*)d_in[3];
    const int*   ea  = (const int*)d_in[4];
    // d_in[5] edge_type unused by reference
    const float* Wm  = (const float*)d_in[6];
    const float* bm  = (const float*)d_in[7];
    const float* aw  = (const float*)d_in[8];
    const float* Wr  = (const float*)d_in[9];
    const float* br  = (const float*)d_in[10];
    const float* eg  = (const float*)d_in[11];
    const float* eb  = (const float*)d_in[12];
    const float* rg  = (const float*)d_in[13];
    const float* rb  = (const float*)d_in[14];
    float* out = (float*)d_out;
    float* ws  = (float*)d_ws;

    hipMemsetAsync(ws + OFF_SUMS, 0, 512 * sizeof(float), stream);            // all stat slots
    hipMemsetAsync(ws + OFF_CS, 0, (size_t)N_NODES * sizeof(float), stream);
    hipMemsetAsync(ws + OFF_ACC, 0, (size_t)N_NODES * 64 * sizeof(float), stream);

    k_prep<<<1, 64, 0, stream>>>(aw, bm, que, ws);
    k_pr<<<125, 256, 0, stream>>>(r, Wm, aw, ws);
    k_px<<<3125, 256, 0, stream>>>(x, Wm, aw, ws);
    k_edge1<<<(N_EDGES + 255) / 256, 256, 0, stream>>>(ei, ea, ws);
    k_edge2<<<N_EDGES / 4, 256, 0, stream>>>(ei, ea, ws);
    k_stats<<<(N_NODES + 63) / 64, 256, 0, stream>>>(bm, ws);
    k_rpre<<<125, 256, 0, stream>>>(r, Wr, br, ws);
    k_bnfin<<<1, 128, 0, stream>>>(ws, eg, eb, rg, rb);
    k_xout<<<(N_NODES + 63) / 64, 256, 0, stream>>>(bm, ws, out);
    k_rout<<<125, 256, 0, stream>>>(ws, out);
}

// Round 6
// 521.482 us; speedup vs baseline: 1.1074x; 1.1074x over previous
//
#include <hip/hip_runtime.h>
#include <hip/hip_fp16.h>

#define N_NODES 100000
#define N_RELS  500
#define N_EDGES 1000000
#define SRCMASK 131071  // 2^17-1

// workspace layout (float offsets)
#define OFF_C     0         // 1
#define OFF_SUMS  64        // 64
#define OFF_SUMSQ 128       // 64
#define OFF_SS    192       // 128 (scale|shift, x-branch)
#define OFF_RSUM  320       // 64
#define OFF_RSQ   384       // 64
#define OFF_RSS   448       // 128 (scale|shift, r-branch)
#define OFF_SR    576       // 500
#define OFF_RP    1088      // 32000 (r-branch pre-BN)
#define OFF_SX    33152     // 100000 (fp32)
#define OFF_DEG   133152    // 100000 ints; rewritten to cursor by k_scan
#define OFF_OFF   233216    // 100001 ints (CSR offsets)
#define OFF_META  333248    // 1M uint2 (a_bits, src|at<<17) = 2M uints
#define OFF_PRH   2333248   // 32000 halves (16000 floats)
#define OFF_PXH   2349280   // 6.4M halves (3.2M floats)
#define OFF_ACC   5549280   // 6.4M fp32 (pre-BN p rows)
// total 11,949,280 floats = 45.6 MiB

// ---- c = b_m . aw_m + aw_q . que -------------------------------------------
__global__ void k_prep(const float* __restrict__ aw, const float* __restrict__ bm,
                       const float* __restrict__ que, float* __restrict__ ws) {
    int t = threadIdx.x;  // 64
    float v = aw[t] * bm[t] + aw[64 + t] * que[t];
    for (int o = 32; o > 0; o >>= 1) v += __shfl_down(v, o);
    if (t == 0) ws[OFF_C] = v;
}

// ---- pr (fp16) + sr ---------------------------------------------------------
__global__ void __launch_bounds__(256) k_pr(const float* __restrict__ r, const float* __restrict__ Wm,
                                            const float* __restrict__ aw, float* __restrict__ ws) {
    __shared__ float w[64][65];
    __shared__ float awl[64];
    int tid = threadIdx.x;
    for (int i = tid; i < 4096; i += 256) w[i >> 6][i & 63] = Wm[(i >> 6) * 128 + 64 + (i & 63)];
    if (tid < 64) awl[tid] = aw[tid];
    __syncthreads();
    int lane = tid & 63, wv = tid >> 6;
    int i = blockIdx.x * 4 + wv;  // grid 125 -> exactly 500
    float rv = r[i * 64 + lane];
    float p = 0.f;
#pragma unroll
    for (int k = 0; k < 64; ++k) p += w[lane][k] * __shfl(rv, k);
    __half* prh = (__half*)(ws + OFF_PRH);
    prh[i * 64 + lane] = __float2half(p);
    float t = p * awl[lane];
    for (int o = 32; o > 0; o >>= 1) t += __shfl_down(t, o);
    if (lane == 0) ws[OFF_SR + i] = t;
}

// ---- px (fp16) + sx ---------------------------------------------------------
__global__ void __launch_bounds__(256) k_px(const float* __restrict__ x, const float* __restrict__ Wm,
                                            const float* __restrict__ aw, float* __restrict__ ws) {
    __shared__ float w[64][65];
    __shared__ float awl[64];
    int tid = threadIdx.x;
    for (int i = tid; i < 4096; i += 256) w[i >> 6][i & 63] = Wm[(i >> 6) * 128 + (i & 63)];
    if (tid < 64) awl[tid] = aw[tid];
    __syncthreads();
    int lane = tid & 63, wv = tid >> 6;
    __half* pxh = (__half*)(ws + OFF_PXH);
    int base = blockIdx.x * 32 + wv * 8;  // grid 3125 -> exactly 100000
    for (int nn = 0; nn < 8; ++nn) {
        int n = base + nn;
        float xv = x[(size_t)n * 64 + lane];
        float p = 0.f;
#pragma unroll
        for (int k = 0; k < 64; ++k) p += w[lane][k] * __shfl(xv, k);
        pxh[(size_t)n * 64 + lane] = __float2half(p);
        float t = p * awl[lane];
        for (int o = 32; o > 0; o >>= 1) t += __shfl_down(t, o);
        if (lane == 0) ws[OFF_SX + n] = t;
    }
}

// ---- histogram of targets ---------------------------------------------------
__global__ void __launch_bounds__(256) k_hist(const int* __restrict__ ei, int* __restrict__ deg) {
    int e = blockIdx.x * 256 + threadIdx.x;
    if (e >= N_EDGES) return;
    atomicAdd(&deg[ei[N_EDGES + e]], 1);
}

// ---- single-block exclusive scan: off[] = scan(deg), cursor(=deg) = off -----
__global__ void __launch_bounds__(1024) k_scan(int* __restrict__ degcur, int* __restrict__ off) {
    __shared__ int ts[1024];
    int tid = threadIdx.x;
    int base = tid * 100;
    int s = 0;
    if (tid < 1000) {
        const int4* d4 = (const int4*)(degcur + base);
#pragma unroll
        for (int j = 0; j < 25; ++j) { int4 b = d4[j]; s += b.x + b.y + b.z + b.w; }
    }
    ts[tid] = s;
    __syncthreads();
    for (int o = 1; o < 1024; o <<= 1) {
        int v = (tid >= o) ? ts[tid - o] : 0;
        __syncthreads();
        ts[tid] += v;
        __syncthreads();
    }
    if (tid == 1023) off[N_NODES] = ts[1023];
    if (tid < 1000) {
        int run = ts[tid] - s;  // exclusive prefix
        const int4* d4 = (const int4*)(degcur + base);
        int4* o4 = (int4*)(off + base);
        int4* c4 = (int4*)(degcur + base);
#pragma unroll
        for (int j = 0; j < 25; ++j) {
            int4 b = d4[j], w;
            w.x = run; run += b.x;
            w.y = run; run += b.y;
            w.z = run; run += b.z;
            w.w = run; run += b.w;
            o4[j] = w;
            c4[j] = w;
        }
    }
}

// ---- scatter: meta[pos] = (a_bits, src|at<<17) sorted by target -------------
__global__ void __launch_bounds__(256) k_scatter(const int* __restrict__ ei, const int* __restrict__ ea,
                                                 const float* __restrict__ ws, int* __restrict__ cursor,
                                                 uint2* __restrict__ meta) {
    int e = blockIdx.x * 256 + threadIdx.x;
    if (e >= N_EDGES) return;
    int src = ei[e], tgt = ei[N_EDGES + e], at = ea[e];
    float a = __expf(tanhf(ws[OFF_SX + src] + ws[OFF_SR + at] + ws[OFF_C]));
    int pos = atomicAdd(&cursor[tgt], 1);
    meta[pos] = make_uint2(__float_as_uint(a), (unsigned)src | ((unsigned)at << 17));
}

// ---- main: per-target register accumulate, write pre-BN rows + stats --------
__global__ void __launch_bounds__(256) k_main(const int* __restrict__ off, const uint2* __restrict__ meta,
                                              const float* __restrict__ bm, float* __restrict__ ws) {
    __shared__ float bsum[64], bsq[64];
    int tid = threadIdx.x;
    int lane = tid & 63, wv = tid >> 6;
    if (tid < 64) { bsum[tid] = 0.f; bsq[tid] = 0.f; }
    __syncthreads();
    const __half* pxh = (const __half*)(ws + OFF_PXH);
    const __half* prh = (const __half*)(ws + OFF_PRH);
    float bm_l = bm[lane];
    float ls = 0.f, lq = 0.f;
    int t0 = blockIdx.x * 32 + wv * 8;  // grid 3125 -> exactly 100000 targets
#pragma unroll 1
    for (int g = 0; g < 8; ++g) {
        int t = t0 + g;
        int s = off[t], e = off[t + 1];
        float acc = 0.f, asum = 0.f;
        for (int i = s; i < e; ++i) {
            uint2 mv = meta[i];
            float a = __uint_as_float(mv.x);
            int src = mv.y & SRCMASK;
            int at = mv.y >> 17;
            float pxv = __half2float(pxh[(size_t)src * 64 + lane]);
            float prv = __half2float(prh[at * 64 + lane]);
            acc += a * (pxv + prv);
            asum += a;
        }
        float p = (e > s) ? (acc / asum + bm_l) : 0.f;
        ws[OFF_ACC + (size_t)t * 64 + lane] = p;
        ls += p;
        lq += p * p;
    }
    atomicAdd(&bsum[lane], ls);
    atomicAdd(&bsq[lane], lq);
    __syncthreads();
    if (tid < 64) {
        atomicAdd(&ws[OFF_SUMS + tid], bsum[tid]);
        atomicAdd(&ws[OFF_SUMSQ + tid], bsq[tid]);
    }
}

// ---- r-branch: pre-BN GEMM + column stats ----------------------------------
__global__ void __launch_bounds__(256) k_rpre(const float* __restrict__ r, const float* __restrict__ Wr,
                                              const float* __restrict__ br, float* __restrict__ ws) {
    __shared__ float w[64][65];
    int tid = threadIdx.x;
    for (int i = tid; i < 4096; i += 256) w[i >> 6][i & 63] = Wr[(i >> 6) * 64 + (i & 63)];
    __syncthreads();
    int lane = tid & 63, wv = tid >> 6;
    int i = blockIdx.x * 4 + wv;  // grid 125 -> exactly 500
    float rv = r[i * 64 + lane];
    float p = br[lane];
#pragma unroll
    for (int k = 0; k < 64; ++k) p += w[lane][k] * __shfl(rv, k);
    ws[OFF_RP + i * 64 + lane] = p;
    atomicAdd(&ws[OFF_RSUM + lane], p);
    atomicAdd(&ws[OFF_RSQ + lane], p * p);
}

// ---- finalize both BN scale/shift ------------------------------------------
__global__ void k_bnfin(float* __restrict__ ws, const float* __restrict__ eg, const float* __restrict__ eb,
                        const float* __restrict__ rg, const float* __restrict__ rb) {
    int tid = threadIdx.x;  // 128
    if (tid < 64) {
        int j = tid;
        float mean = ws[OFF_SUMS + j] * (1.f / N_NODES);
        float var = ws[OFF_SUMSQ + j] * (1.f / N_NODES) - mean * mean;
        float sc = rsqrtf(var + 1e-5f) * eg[j];
        ws[OFF_SS + j] = sc;
        ws[OFF_SS + 64 + j] = eb[j] - mean * sc;
    } else {
        int j = tid - 64;
        float mean = ws[OFF_RSUM + j] * (1.f / N_RELS);
        float var = ws[OFF_RSQ + j] * (1.f / N_RELS) - mean * mean;
        float sc = rsqrtf(var + 1e-5f) * rg[j];
        ws[OFF_RSS + j] = sc;
        ws[OFF_RSS + 64 + j] = rb[j] - mean * sc;
    }
}

// ---- x-branch output --------------------------------------------------------
__global__ void __launch_bounds__(256) k_xout(const float* __restrict__ ws, float* __restrict__ out) {
    __shared__ float sc[64], sh[64];
    int tid = threadIdx.x;
    if (tid < 64) { sc[tid] = ws[OFF_SS + tid]; sh[tid] = ws[OFF_SS + 64 + tid]; }
    __syncthreads();
    int lane = tid & 63, wv = tid >> 6;
    int base = blockIdx.x * 64;
    for (int it = 0; it < 16; ++it) {
        int t = base + it * 4 + wv;
        if (t < N_NODES) {
            float p = ws[OFF_ACC + (size_t)t * 64 + lane];
            out[(size_t)t * 64 + lane] = tanhf(p * sc[lane] + sh[lane]);
        }
    }
}

// ---- r-branch output --------------------------------------------------------
__global__ void __launch_bounds__(256) k_rout(const float* __restrict__ ws, float* __restrict__ out) {
    __shared__ float sc[64], sh[64];
    int tid = threadIdx.x;
    if (tid < 64) { sc[tid] = ws[OFF_RSS + tid]; sh[tid] = ws[OFF_RSS + 64 + tid]; }
    __syncthreads();
    int lane = tid & 63, wv = tid >> 6;
    int i = blockIdx.x * 4 + wv;  // grid 125
    float p = ws[OFF_RP + i * 64 + lane];
    out[(size_t)N_NODES * 64 + (size_t)i * 64 + lane] = tanhf(p * sc[lane] + sh[lane]);
}

extern "C" void kernel_launch(void* const* d_in, const int* in_sizes, int n_in,
                              void* d_out, int out_size, void* d_ws, size_t ws_size,
                              hipStream_t stream) {
    const float* x   = (const float*)d_in[0];
    const float* r   = (const float*)d_in[1];
    const float* que = (const float*)d_in[2];
    const int*   ei  = (const int*)d_in[3];
    const int*   ea  = (const int*)d_in[4];
    // d_in[5] edge_type unused by reference
    const float* Wm  = (const float*)d_in[6];
    const float* bm  = (const float*)d_in[7];
    const float* aw  = (const float*)d_in[8];
    const float* Wr  = (const float*)d_in[9];
    const float* br  = (const float*)d_in[10];
    const float* eg  = (const float*)d_in[11];
    const float* eb  = (const float*)d_in[12];
    const float* rg  = (const float*)d_in[13];
    const float* rb  = (const float*)d_in[14];
    float* out = (float*)d_out;
    float* ws  = (float*)d_ws;
    int*   deg = (int*)(ws + OFF_DEG);
    int*   off = (int*)(ws + OFF_OFF);
    uint2* meta = (uint2*)(ws + OFF_META);

    hipMemsetAsync(ws + OFF_SUMS, 0, 512 * sizeof(float), stream);  // all stat slots
    hipMemsetAsync(deg, 0, (size_t)N_NODES * sizeof(int), stream);

    k_hist<<<(N_EDGES + 255) / 256, 256, 0, stream>>>(ei, deg);
    k_prep<<<1, 64, 0, stream>>>(aw, bm, que, ws);
    k_pr<<<125, 256, 0, stream>>>(r, Wm, aw, ws);
    k_px<<<3125, 256, 0, stream>>>(x, Wm, aw, ws);
    k_scan<<<1, 1024, 0, stream>>>(deg, off);
    k_scatter<<<(N_EDGES + 255) / 256, 256, 0, stream>>>(ei, ea, ws, deg, meta);
    k_main<<<3125, 256, 0, stream>>>(off, meta, bm, ws);
    k_rpre<<<125, 256, 0, stream>>>(r, Wr, br, ws);
    k_bnfin<<<1, 128, 0, stream>>>(ws, eg, eb, rg, rb);
    k_xout<<<(N_NODES + 63) / 64, 256, 0, stream>>>(ws, out);
    k_rout<<<125, 256, 0, stream>>>(ws, out);
}

// Round 8
// 446.882 us; speedup vs baseline: 1.2923x; 1.1669x over previous
//
#include <hip/hip_runtime.h>
#include <hip/hip_fp16.h>

#define N_NODES 100000
#define N_RELS  500
#define N_EDGES 1000000
#define SRCMASK 131071  // 2^17-1

// workspace layout (float offsets)
#define OFF_C     0         // 1
#define OFF_SUMS  64        // 64
#define OFF_SUMSQ 128       // 64
#define OFF_RSUM  320       // 64
#define OFF_RSQ   384       // 64
#define OFF_SR    576       // 500
#define OFF_RP    1088      // 32000 (r-branch pre-BN)
#define OFF_SX    33152     // 100000 (fp32)
#define OFF_DEG   133152    // 100000 ints; rewritten to cursor by k_scan
#define OFF_OFF   233216    // 100001 ints (CSR offsets)
#define OFF_META  333248    // 1M uint2 = 2M uints
#define OFF_PRH   2333248   // 32000 halves
#define OFF_PXH   2349280   // 6.4M halves
#define OFF_ACCH  5549280   // 6.4M halves (pre-BN p rows, fp16)
// total 8,749,280 floats = 33.4 MiB

// ---- fused rel-kernel: pr(fp16)+sr (from Wm right half), rp+stats (Wr), c --
__global__ void __launch_bounds__(256) k_rel(const float* __restrict__ r, const float* __restrict__ Wm,
                                             const float* __restrict__ Wr, const float* __restrict__ br,
                                             const float* __restrict__ aw, const float* __restrict__ bm,
                                             const float* __restrict__ que, float* __restrict__ ws) {
    __shared__ float wm[64][65];
    __shared__ float wr[64][65];
    __shared__ float awl[64];
    int tid = threadIdx.x;
    for (int i = tid; i < 4096; i += 256) {
        int row = i >> 6, col = i & 63;
        wm[row][col] = Wm[row * 128 + 64 + col];
        wr[row][col] = Wr[row * 64 + col];
    }
    if (tid < 64) awl[tid] = aw[tid];
    __syncthreads();
    int lane = tid & 63, wv = tid >> 6;
    int i = blockIdx.x * 4 + wv;  // grid 125 -> exactly 500
    float rv = r[i * 64 + lane];
    float p = 0.f, q = br[lane];
#pragma unroll
    for (int k = 0; k < 64; ++k) {
        float rk = __shfl(rv, k);
        p += wm[lane][k] * rk;
        q += wr[lane][k] * rk;
    }
    __half* prh = (__half*)(ws + OFF_PRH);
    prh[i * 64 + lane] = __float2half(p);
    ws[OFF_RP + i * 64 + lane] = q;
    atomicAdd(&ws[OFF_RSUM + lane], q);
    atomicAdd(&ws[OFF_RSQ + lane], q * q);
    float t = p * awl[lane];
    for (int o = 32; o > 0; o >>= 1) t += __shfl_down(t, o);
    if (lane == 0) ws[OFF_SR + i] = t;
    if (blockIdx.x == 0 && tid < 64) {
        float v = aw[tid] * bm[tid] + aw[64 + tid] * que[tid];
        for (int o = 32; o > 0; o >>= 1) v += __shfl_down(v, o);
        if (tid == 0) ws[OFF_C] = v;
    }
}

// ---- px (fp16) + sx, with target-histogram fused ---------------------------
__global__ void __launch_bounds__(256) k_px(const float* __restrict__ x, const float* __restrict__ Wm,
                                            const float* __restrict__ aw, const int* __restrict__ ei,
                                            float* __restrict__ ws, int* __restrict__ deg) {
    int tid = threadIdx.x;
    // fused histogram: grid-stride over 1M edges (800k threads)
    for (int e = blockIdx.x * 256 + tid; e < N_EDGES; e += 3125 * 256)
        atomicAdd(&deg[ei[N_EDGES + e]], 1);
    __shared__ float w[64][65];
    __shared__ float awl[64];
    for (int i = tid; i < 4096; i += 256) w[i >> 6][i & 63] = Wm[(i >> 6) * 128 + (i & 63)];
    if (tid < 64) awl[tid] = aw[tid];
    __syncthreads();
    int lane = tid & 63, wv = tid >> 6;
    __half* pxh = (__half*)(ws + OFF_PXH);
    int base = blockIdx.x * 32 + wv * 8;  // grid 3125 -> exactly 100000
    for (int nn = 0; nn < 8; ++nn) {
        int n = base + nn;
        float xv = x[(size_t)n * 64 + lane];
        float p = 0.f;
#pragma unroll
        for (int k = 0; k < 64; ++k) p += w[lane][k] * __shfl(xv, k);
        pxh[(size_t)n * 64 + lane] = __float2half(p);
        float t = p * awl[lane];
        for (int o = 32; o > 0; o >>= 1) t += __shfl_down(t, o);
        if (lane == 0) ws[OFF_SX + n] = t;
    }
}

// ---- single-block exclusive scan: off[] = scan(deg), cursor(=deg) = off -----
__global__ void __launch_bounds__(1024) k_scan(int* __restrict__ degcur, int* __restrict__ off) {
    __shared__ int ts[1024];
    int tid = threadIdx.x;
    int base = tid * 100;
    int s = 0;
    if (tid < 1000) {
        const int4* d4 = (const int4*)(degcur + base);
#pragma unroll
        for (int j = 0; j < 25; ++j) { int4 b = d4[j]; s += b.x + b.y + b.z + b.w; }
    }
    ts[tid] = s;
    __syncthreads();
    for (int o = 1; o < 1024; o <<= 1) {
        int v = (tid >= o) ? ts[tid - o] : 0;
        __syncthreads();
        ts[tid] += v;
        __syncthreads();
    }
    if (tid == 1023) off[N_NODES] = ts[1023];
    if (tid < 1000) {
        int run = ts[tid] - s;  // exclusive prefix
        const int4* d4 = (const int4*)(degcur + base);
        int4* o4 = (int4*)(off + base);
        int4* c4 = (int4*)(degcur + base);
#pragma unroll
        for (int j = 0; j < 25; ++j) {
            int4 b = d4[j], w;
            w.x = run; run += b.x;
            w.y = run; run += b.y;
            w.z = run; run += b.z;
            w.w = run; run += b.w;
            o4[j] = w;
            c4[j] = w;
        }
    }
}

// ---- scatter: meta[pos] = (a_bits, src|at<<17) sorted by target -------------
__global__ void __launch_bounds__(256) k_scatter(const int* __restrict__ ei, const int* __restrict__ ea,
                                                 const float* __restrict__ ws, int* __restrict__ cursor,
                                                 uint2* __restrict__ meta) {
    int e = blockIdx.x * 256 + threadIdx.x;
    if (e >= N_EDGES) return;
    int src = ei[e], tgt = ei[N_EDGES + e], at = ea[e];
    float a = __expf(tanhf(ws[OFF_SX + src] + ws[OFF_SR + at] + ws[OFF_C]));
    int pos = atomicAdd(&cursor[tgt], 1);
    meta[pos] = make_uint2(__float_as_uint(a), (unsigned)src | ((unsigned)at << 17));
}

// ---- main: per-target register accumulate (4x unrolled), fp16 rows + stats --
__global__ void __launch_bounds__(256) k_main(const int* __restrict__ off, const uint2* __restrict__ meta,
                                              const float* __restrict__ bm, float* __restrict__ ws) {
    __shared__ float bsum[64], bsq[64];
    int tid = threadIdx.x;
    int lane = tid & 63, wv = tid >> 6;
    if (tid < 64) { bsum[tid] = 0.f; bsq[tid] = 0.f; }
    __syncthreads();
    const __half* pxh = (const __half*)(ws + OFF_PXH);
    const __half* prh = (const __half*)(ws + OFF_PRH);
    __half* acch = (__half*)(ws + OFF_ACCH);
    float bm_l = bm[lane];
    float ls = 0.f, lq = 0.f;
    int t0 = blockIdx.x * 32 + wv * 8;  // grid 3125 -> exactly 100000 targets
#pragma unroll 1
    for (int g = 0; g < 8; ++g) {
        int t = t0 + g;
        int s = off[t], e = off[t + 1];
        float acc = 0.f, asum = 0.f;
        int i = s;
        for (; i + 4 <= e; i += 4) {
            uint2 m0 = meta[i], m1 = meta[i + 1], m2 = meta[i + 2], m3 = meta[i + 3];
            float px0 = __half2float(pxh[(size_t)(m0.y & SRCMASK) * 64 + lane]);
            float pr0 = __half2float(prh[(m0.y >> 17) * 64 + lane]);
            float px1 = __half2float(pxh[(size_t)(m1.y & SRCMASK) * 64 + lane]);
            float pr1 = __half2float(prh[(m1.y >> 17) * 64 + lane]);
            float px2 = __half2float(pxh[(size_t)(m2.y & SRCMASK) * 64 + lane]);
            float pr2 = __half2float(prh[(m2.y >> 17) * 64 + lane]);
            float px3 = __half2float(pxh[(size_t)(m3.y & SRCMASK) * 64 + lane]);
            float pr3 = __half2float(prh[(m3.y >> 17) * 64 + lane]);
            float a0 = __uint_as_float(m0.x), a1 = __uint_as_float(m1.x);
            float a2 = __uint_as_float(m2.x), a3 = __uint_as_float(m3.x);
            acc += a0 * (px0 + pr0) + a1 * (px1 + pr1) + a2 * (px2 + pr2) + a3 * (px3 + pr3);
            asum += (a0 + a1) + (a2 + a3);
        }
        for (; i < e; ++i) {
            uint2 mv = meta[i];
            float a = __uint_as_float(mv.x);
            float pxv = __half2float(pxh[(size_t)(mv.y & SRCMASK) * 64 + lane]);
            float prv = __half2float(prh[(mv.y >> 17) * 64 + lane]);
            acc += a * (pxv + prv);
            asum += a;
        }
        float p = (e > s) ? (acc / asum + bm_l) : 0.f;
        acch[(size_t)t * 64 + lane] = __float2half(p);
        ls += p;
        lq += p * p;
    }
    atomicAdd(&bsum[lane], ls);
    atomicAdd(&bsq[lane], lq);
    __syncthreads();
    if (tid < 64) {
        atomicAdd(&ws[OFF_SUMS + tid], bsum[tid]);
        atomicAdd(&ws[OFF_SUMSQ + tid], bsq[tid]);
    }
}

// ---- x-branch output (BN finalize inlined) ---------------------------------
__global__ void __launch_bounds__(256) k_xout(const float* __restrict__ ws, const float* __restrict__ eg,
                                              const float* __restrict__ eb, float* __restrict__ out) {
    __shared__ float sc[64], sh[64];
    int tid = threadIdx.x;
    if (tid < 64) {
        float mean = ws[OFF_SUMS + tid] * (1.f / N_NODES);
        float var = ws[OFF_SUMSQ + tid] * (1.f / N_NODES) - mean * mean;
        float s = rsqrtf(var + 1e-5f) * eg[tid];
        sc[tid] = s;
        sh[tid] = eb[tid] - mean * s;
    }
    __syncthreads();
    int lane = tid & 63, wv = tid >> 6;
    const __half* acch = (const __half*)(ws + OFF_ACCH);
    int base = blockIdx.x * 64;
    for (int it = 0; it < 16; ++it) {
        int t = base + it * 4 + wv;
        if (t < N_NODES) {
            float p = __half2float(acch[(size_t)t * 64 + lane]);
            out[(size_t)t * 64 + lane] = tanhf(p * sc[lane] + sh[lane]);
        }
    }
}

// ---- r-branch output (BN finalize inlined) ---------------------------------
__global__ void __launch_bounds__(256) k_rout(const float* __restrict__ ws, const float* __restrict__ rg,
                                              const float* __restrict__ rb, float* __restrict__ out) {
    __shared__ float sc[64], sh[64];
    int tid = threadIdx.x;
    if (tid < 64) {
        float mean = ws[OFF_RSUM + tid] * (1.f / N_RELS);
        float var = ws[OFF_RSQ + tid] * (1.f / N_RELS) - mean * mean;
        float s = rsqrtf(var + 1e-5f) * rg[tid];
        sc[tid] = s;
        sh[tid] = rb[tid] - mean * s;
    }
    __syncthreads();
    int lane = tid & 63, wv = tid >> 6;
    int i = blockIdx.x * 4 + wv;  // grid 125
    float p = ws[OFF_RP + i * 64 + lane];
    out[(size_t)N_NODES * 64 + (size_t)i * 64 + lane] = tanhf(p * sc[lane] + sh[lane]);
}

extern "C" void kernel_launch(void* const* d_in, const int* in_sizes, int n_in,
                              void* d_out, int out_size, void* d_ws, size_t ws_size,
                              hipStream_t stream) {
    const float* x   = (const float*)d_in[0];
    const float* r   = (const float*)d_in[1];
    const float* que = (const float*)d_in[2];
    const int*   ei  = (const int*)d_in[3];
    const int*   ea  = (const int*)d_in[4];
    // d_in[5] edge_type unused by reference
    const float* Wm  = (const float*)d_in[6];
    const float* bm  = (const float*)d_in[7];
    const float* aw  = (const float*)d_in[8];
    const float* Wr  = (const float*)d_in[9];
    const float* br  = (const float*)d_in[10];
    const float* eg  = (const float*)d_in[11];
    const float* eb  = (const float*)d_in[12];
    const float* rg  = (const float*)d_in[13];
    const float* rb  = (const float*)d_in[14];
    float* out = (float*)d_out;
    float* ws  = (float*)d_ws;
    int*   deg = (int*)(ws + OFF_DEG);
    int*   off = (int*)(ws + OFF_OFF);
    uint2* meta = (uint2*)(ws + OFF_META);

    hipMemsetAsync(ws + OFF_SUMS, 0, 512 * sizeof(float), stream);  // all stat slots
    hipMemsetAsync(deg, 0, (size_t)N_NODES * sizeof(int), stream);

    k_rel<<<125, 256, 0, stream>>>(r, Wm, Wr, br, aw, bm, que, ws);
    k_px<<<3125, 256, 0, stream>>>(x, Wm, aw, ei, ws, deg);
    k_scan<<<1, 1024, 0, stream>>>(deg, off);
    k_scatter<<<(N_EDGES + 255) / 256, 256, 0, stream>>>(ei, ea, ws, deg, meta);
    k_main<<<3125, 256, 0, stream>>>(off, meta, bm, ws);
    k_xout<<<(N_NODES + 63) / 64, 256, 0, stream>>>(ws, eg, eb, out);
    k_rout<<<125, 256, 0, stream>>>(ws, rg, rb, out);
}

// Round 9
// 364.460 us; speedup vs baseline: 1.5845x; 1.2261x over previous
//
#include <hip/hip_runtime.h>
#include <hip/hip_fp16.h>

#define N_NODES 100000
#define N_RELS  500
#define N_EDGES 1000000
#define SRCMASK 131071  // 2^17-1

// workspace layout (float offsets)
#define OFF_C     0         // 1
#define OFF_SUMS  64        // 64
#define OFF_SUMSQ 128       // 64
#define OFF_RSUM  320       // 64
#define OFF_RSQ   384       // 64
#define OFF_SR    576       // 500
#define OFF_RP    1088      // 32000 (r-branch pre-BN)
#define OFF_SX    33152     // 100000 (fp32)
#define OFF_DEG   133152    // 100000 ints; rewritten to cursor by scan3
#define OFF_OFF   233216    // 100001 ints (CSR offsets)
#define OFF_META  333248    // 1M uint2 = 2M uints
#define OFF_PRH   2333248   // 32000 halves
#define OFF_PXH   2349280   // 6.4M halves
#define OFF_ACCH  5549280   // 6.4M halves (pre-BN p rows, fp16)
#define OFF_PART  8749280   // 128 ints (scan partials)
// total ~8,749,408 floats = 33.4 MiB

typedef _Float16 h8 __attribute__((ext_vector_type(8)));
typedef float f4 __attribute__((ext_vector_type(4)));

// ---- fused rel-kernel: pr(fp16)+sr (from Wm right half), rp+stats (Wr), c --
__global__ void __launch_bounds__(256) k_rel(const float* __restrict__ r, const float* __restrict__ Wm,
                                             const float* __restrict__ Wr, const float* __restrict__ br,
                                             const float* __restrict__ aw, const float* __restrict__ bm,
                                             const float* __restrict__ que, float* __restrict__ ws) {
    __shared__ float wm[64][65];
    __shared__ float wr[64][65];
    __shared__ float awl[64];
    int tid = threadIdx.x;
    for (int i = tid; i < 4096; i += 256) {
        int row = i >> 6, col = i & 63;
        wm[row][col] = Wm[row * 128 + 64 + col];
        wr[row][col] = Wr[row * 64 + col];
    }
    if (tid < 64) awl[tid] = aw[tid];
    __syncthreads();
    int lane = tid & 63, wv = tid >> 6;
    int i = blockIdx.x * 4 + wv;  // grid 125 -> exactly 500
    float rv = r[i * 64 + lane];
    float p = 0.f, q = br[lane];
#pragma unroll
    for (int k = 0; k < 64; ++k) {
        float rk = __shfl(rv, k);
        p += wm[lane][k] * rk;
        q += wr[lane][k] * rk;
    }
    __half* prh = (__half*)(ws + OFF_PRH);
    prh[i * 64 + lane] = __float2half(p);
    ws[OFF_RP + i * 64 + lane] = q;
    atomicAdd(&ws[OFF_RSUM + lane], q);
    atomicAdd(&ws[OFF_RSQ + lane], q * q);
    float t = p * awl[lane];
    for (int o = 32; o > 0; o >>= 1) t += __shfl_down(t, o);
    if (lane == 0) ws[OFF_SR + i] = t;
    if (blockIdx.x == 0 && tid < 64) {
        float v = aw[tid] * bm[tid] + aw[64 + tid] * que[tid];
        for (int o = 32; o > 0; o >>= 1) v += __shfl_down(v, o);
        if (tid == 0) ws[OFF_C] = v;
    }
}

// ---- px via fp16 MFMA: px[n][c] = sum_k x[n][k] * Wm[c][k]; sx = px . aw ---
__global__ void __launch_bounds__(128) k_px(const float* __restrict__ x, const float* __restrict__ Wm,
                                            const float* __restrict__ aw, float* __restrict__ ws) {
    int tid = threadIdx.x;
    int lane = tid & 63, wv = tid >> 6;
    int wtile = blockIdx.x * 2 + wv;  // grid 3125 -> 6250 tiles of 16 nodes
    int n0 = wtile * 16;
    int rrow = lane & 15, grp = lane >> 4;  // grp 0..3

    // B fragments: B[k][col] = Wm[col][k]; lane: col=rrow(+16ct), k=h*32+grp*8+j
    h8 bfr[4][2];
    float awv[4];
#pragma unroll
    for (int ct = 0; ct < 4; ++ct) {
        int col = ct * 16 + rrow;
        awv[ct] = aw[col];
        const float* wp = Wm + col * 128;
#pragma unroll
        for (int h = 0; h < 2; ++h) {
            f4 w0 = *(const f4*)(wp + h * 32 + grp * 8);
            f4 w1 = *(const f4*)(wp + h * 32 + grp * 8 + 4);
            h8 b;
#pragma unroll
            for (int j = 0; j < 4; ++j) { b[j] = (_Float16)w0[j]; b[4 + j] = (_Float16)w1[j]; }
            bfr[ct][h] = b;
        }
    }
    // A fragments: lane: row(node)=n0+rrow, k=h*32+grp*8+j
    const float* xp = x + (size_t)(n0 + rrow) * 64;
    h8 afr[2];
#pragma unroll
    for (int h = 0; h < 2; ++h) {
        f4 a0 = *(const f4*)(xp + h * 32 + grp * 8);
        f4 a1 = *(const f4*)(xp + h * 32 + grp * 8 + 4);
        h8 a;
#pragma unroll
        for (int j = 0; j < 4; ++j) { a[j] = (_Float16)a0[j]; a[4 + j] = (_Float16)a1[j]; }
        afr[h] = a;
    }
    f4 acc[4];
#pragma unroll
    for (int ct = 0; ct < 4; ++ct) acc[ct] = (f4){0.f, 0.f, 0.f, 0.f};
#pragma unroll
    for (int h = 0; h < 2; ++h)
#pragma unroll
        for (int ct = 0; ct < 4; ++ct)
            acc[ct] = __builtin_amdgcn_mfma_f32_16x16x32_f16(afr[h], bfr[ct][h], acc[ct], 0, 0, 0);

    // D: col = ct*16 + (lane&15), row(node) = n0 + grp*4 + q (q = reg idx)
    __half* pxh = (__half*)(ws + OFF_PXH);
#pragma unroll
    for (int q = 0; q < 4; ++q) {
        int node = n0 + grp * 4 + q;
#pragma unroll
        for (int ct = 0; ct < 4; ++ct)
            pxh[(size_t)node * 64 + ct * 16 + rrow] = __float2half(acc[ct][q]);
        float t = acc[0][q] * awv[0] + acc[1][q] * awv[1] + acc[2][q] * awv[2] + acc[3][q] * awv[3];
        t += __shfl_xor(t, 1); t += __shfl_xor(t, 2); t += __shfl_xor(t, 4); t += __shfl_xor(t, 8);
        if (rrow == 0) ws[OFF_SX + node] = t;
    }
}

// ---- histogram of targets ---------------------------------------------------
__global__ void __launch_bounds__(256) k_hist(const int* __restrict__ ei, int* __restrict__ deg) {
    int e = blockIdx.x * 256 + threadIdx.x;
    if (e >= N_EDGES) return;
    atomicAdd(&deg[ei[N_EDGES + e]], 1);
}

// ---- scan phase 1: per-block (1000 nodes) local exclusive scan --------------
__global__ void __launch_bounds__(256) k_scan1(const int* __restrict__ deg, int* __restrict__ off,
                                               int* __restrict__ part) {
    __shared__ int ts[256];
    int tid = threadIdx.x;
    int idx0 = blockIdx.x * 1000 + tid * 4;
    int4 d = make_int4(0, 0, 0, 0);
    if (tid < 250) d = *(const int4*)(deg + idx0);
    int s = d.x + d.y + d.z + d.w;
    ts[tid] = s;
    __syncthreads();
    for (int o = 1; o < 256; o <<= 1) {
        int v = (tid >= o) ? ts[tid - o] : 0;
        __syncthreads();
        ts[tid] += v;
        __syncthreads();
    }
    int excl = ts[tid] - s;
    if (tid < 250) {
        off[idx0] = excl;
        off[idx0 + 1] = excl + d.x;
        off[idx0 + 2] = excl + d.x + d.y;
        off[idx0 + 3] = excl + d.x + d.y + d.z;
    }
    if (tid == 255) part[blockIdx.x] = ts[255];
}

// ---- scan phase 2: scan the 100 block totals --------------------------------
__global__ void __launch_bounds__(128) k_scan2(int* __restrict__ part, int* __restrict__ off) {
    __shared__ int ts[128];
    int tid = threadIdx.x;
    int v = (tid < 100) ? part[tid] : 0;
    ts[tid] = v;
    __syncthreads();
    for (int o = 1; o < 128; o <<= 1) {
        int u = (tid >= o) ? ts[tid - o] : 0;
        __syncthreads();
        ts[tid] += u;
        __syncthreads();
    }
    if (tid < 100) part[tid] = ts[tid] - v;  // exclusive base
    if (tid == 127) off[N_NODES] = ts[127];
}

// ---- scan phase 3: add base, write cursor -----------------------------------
__global__ void __launch_bounds__(256) k_scan3(int* __restrict__ off, const int* __restrict__ part,
                                               int* __restrict__ cursor) {
    int i = blockIdx.x * 256 + threadIdx.x;
    if (i >= N_NODES) return;
    int v = off[i] + part[i / 1000];
    off[i] = v;
    cursor[i] = v;
}

// ---- scatter: meta[pos] = (a_bits, src|at<<17) sorted by target -------------
__global__ void __launch_bounds__(256) k_scatter(const int* __restrict__ ei, const int* __restrict__ ea,
                                                 const float* __restrict__ ws, int* __restrict__ cursor,
                                                 uint2* __restrict__ meta) {
    int e = blockIdx.x * 256 + threadIdx.x;
    if (e >= N_EDGES) return;
    int src = ei[e], tgt = ei[N_EDGES + e], at = ea[e];
    float a = __expf(tanhf(ws[OFF_SX + src] + ws[OFF_SR + at] + ws[OFF_C]));
    int pos = atomicAdd(&cursor[tgt], 1);
    meta[pos] = make_uint2(__float_as_uint(a), (unsigned)src | ((unsigned)at << 17));
}

// ---- main: per-target register accumulate (4x unrolled), fp16 rows + stats --
__global__ void __launch_bounds__(256) k_main(const int* __restrict__ off, const uint2* __restrict__ meta,
                                              const float* __restrict__ bm, float* __restrict__ ws) {
    __shared__ float bsum[64], bsq[64];
    int tid = threadIdx.x;
    int lane = tid & 63, wv = tid >> 6;
    if (tid < 64) { bsum[tid] = 0.f; bsq[tid] = 0.f; }
    __syncthreads();
    const __half* pxh = (const __half*)(ws + OFF_PXH);
    const __half* prh = (const __half*)(ws + OFF_PRH);
    __half* acch = (__half*)(ws + OFF_ACCH);
    float bm_l = bm[lane];
    float ls = 0.f, lq = 0.f;
    int t0 = blockIdx.x * 32 + wv * 8;  // grid 3125 -> exactly 100000 targets
#pragma unroll 1
    for (int g = 0; g < 8; ++g) {
        int t = t0 + g;
        int s = off[t], e = off[t + 1];
        float acc = 0.f, asum = 0.f;
        int i = s;
        for (; i + 4 <= e; i += 4) {
            uint2 m0 = meta[i], m1 = meta[i + 1], m2 = meta[i + 2], m3 = meta[i + 3];
            float px0 = __half2float(pxh[(size_t)(m0.y & SRCMASK) * 64 + lane]);
            float pr0 = __half2float(prh[(m0.y >> 17) * 64 + lane]);
            float px1 = __half2float(pxh[(size_t)(m1.y & SRCMASK) * 64 + lane]);
            float pr1 = __half2float(prh[(m1.y >> 17) * 64 + lane]);
            float px2 = __half2float(pxh[(size_t)(m2.y & SRCMASK) * 64 + lane]);
            float pr2 = __half2float(prh[(m2.y >> 17) * 64 + lane]);
            float px3 = __half2float(pxh[(size_t)(m3.y & SRCMASK) * 64 + lane]);
            float pr3 = __half2float(prh[(m3.y >> 17) * 64 + lane]);
            float a0 = __uint_as_float(m0.x), a1 = __uint_as_float(m1.x);
            float a2 = __uint_as_float(m2.x), a3 = __uint_as_float(m3.x);
            acc += a0 * (px0 + pr0) + a1 * (px1 + pr1) + a2 * (px2 + pr2) + a3 * (px3 + pr3);
            asum += (a0 + a1) + (a2 + a3);
        }
        for (; i < e; ++i) {
            uint2 mv = meta[i];
            float a = __uint_as_float(mv.x);
            float pxv = __half2float(pxh[(size_t)(mv.y & SRCMASK) * 64 + lane]);
            float prv = __half2float(prh[(mv.y >> 17) * 64 + lane]);
            acc += a * (pxv + prv);
            asum += a;
        }
        float p = (e > s) ? (acc / asum + bm_l) : 0.f;
        acch[(size_t)t * 64 + lane] = __float2half(p);
        ls += p;
        lq += p * p;
    }
    atomicAdd(&bsum[lane], ls);
    atomicAdd(&bsq[lane], lq);
    __syncthreads();
    if (tid < 64) {
        atomicAdd(&ws[OFF_SUMS + tid], bsum[tid]);
        atomicAdd(&ws[OFF_SUMSQ + tid], bsq[tid]);
    }
}

// ---- x-branch output (BN finalize inlined) ---------------------------------
__global__ void __launch_bounds__(256) k_xout(const float* __restrict__ ws, const float* __restrict__ eg,
                                              const float* __restrict__ eb, float* __restrict__ out) {
    __shared__ float sc[64], sh[64];
    int tid = threadIdx.x;
    if (tid < 64) {
        float mean = ws[OFF_SUMS + tid] * (1.f / N_NODES);
        float var = ws[OFF_SUMSQ + tid] * (1.f / N_NODES) - mean * mean;
        float s = rsqrtf(var + 1e-5f) * eg[tid];
        sc[tid] = s;
        sh[tid] = eb[tid] - mean * s;
    }
    __syncthreads();
    int lane = tid & 63, wv = tid >> 6;
    const __half* acch = (const __half*)(ws + OFF_ACCH);
    int base = blockIdx.x * 64;
    for (int it = 0; it < 16; ++it) {
        int t = base + it * 4 + wv;
        if (t < N_NODES) {
            float p = __half2float(acch[(size_t)t * 64 + lane]);
            out[(size_t)t * 64 + lane] = tanhf(p * sc[lane] + sh[lane]);
        }
    }
}

// ---- r-branch output (BN finalize inlined) ---------------------------------
__global__ void __launch_bounds__(256) k_rout(const float* __restrict__ ws, const float* __restrict__ rg,
                                              const float* __restrict__ rb, float* __restrict__ out) {
    __shared__ float sc[64], sh[64];
    int tid = threadIdx.x;
    if (tid < 64) {
        float mean = ws[OFF_RSUM + tid] * (1.f / N_RELS);
        float var = ws[OFF_RSQ + tid] * (1.f / N_RELS) - mean * mean;
        float s = rsqrtf(var + 1e-5f) * rg[tid];
        sc[tid] = s;
        sh[tid] = rb[tid] - mean * s;
    }
    __syncthreads();
    int lane = tid & 63, wv = tid >> 6;
    int i = blockIdx.x * 4 + wv;  // grid 125
    float p = ws[OFF_RP + i * 64 + lane];
    out[(size_t)N_NODES * 64 + (size_t)i * 64 + lane] = tanhf(p * sc[lane] + sh[lane]);
}

extern "C" void kernel_launch(void* const* d_in, const int* in_sizes, int n_in,
                              void* d_out, int out_size, void* d_ws, size_t ws_size,
                              hipStream_t stream) {
    const float* x   = (const float*)d_in[0];
    const float* r   = (const float*)d_in[1];
    const float* que = (const float*)d_in[2];
    const int*   ei  = (const int*)d_in[3];
    const int*   ea  = (const int*)d_in[4];
    // d_in[5] edge_type unused by reference
    const float* Wm  = (const float*)d_in[6];
    const float* bm  = (const float*)d_in[7];
    const float* aw  = (const float*)d_in[8];
    const float* Wr  = (const float*)d_in[9];
    const float* br  = (const float*)d_in[10];
    const float* eg  = (const float*)d_in[11];
    const float* eb  = (const float*)d_in[12];
    const float* rg  = (const float*)d_in[13];
    const float* rb  = (const float*)d_in[14];
    float* out = (float*)d_out;
    float* ws  = (float*)d_ws;
    int*   deg  = (int*)(ws + OFF_DEG);
    int*   off  = (int*)(ws + OFF_OFF);
    int*   part = (int*)(ws + OFF_PART);
    uint2* meta = (uint2*)(ws + OFF_META);

    hipMemsetAsync(ws + OFF_SUMS, 0, 512 * sizeof(float), stream);  // all stat slots
    hipMemsetAsync(deg, 0, (size_t)N_NODES * sizeof(int), stream);

    k_rel<<<125, 256, 0, stream>>>(r, Wm, Wr, br, aw, bm, que, ws);
    k_px<<<3125, 128, 0, stream>>>(x, Wm, aw, ws);
    k_hist<<<(N_EDGES + 255) / 256, 256, 0, stream>>>(ei, deg);
    k_scan1<<<100, 256, 0, stream>>>(deg, off, part);
    k_scan2<<<1, 128, 0, stream>>>(part, off);
    k_scan3<<<(N_NODES + 255) / 256, 256, 0, stream>>>(off, part, deg);
    k_scatter<<<(N_EDGES + 255) / 256, 256, 0, stream>>>(ei, ea, ws, deg, meta);
    k_main<<<3125, 256, 0, stream>>>(off, meta, bm, ws);
    k_xout<<<(N_NODES + 63) / 64, 256, 0, stream>>>(ws, eg, eb, out);
    k_rout<<<125, 256, 0, stream>>>(ws, rg, rb, out);
}